// Round 1
// 132.541 us; speedup vs baseline: 1.0657x; 1.0657x over previous
//
#include <hip/hip_runtime.h>
#include <hip/hip_bf16.h>
#include <math.h>

#define D_MODEL 1024
#define NUM_HEADS 16
#define DK 64
#define BATCH 2
#define SEQ 2048
#define MROWS (BATCH * SEQ)   // 4096

// Q projection pre-scale: 1/sqrt(dk) * log2(e)  -> scores arrive in log2 domain
#define QSCALE (0.125f * 1.4426950408889634f)

typedef __attribute__((ext_vector_type(8))) short bf16x8;
typedef __attribute__((ext_vector_type(4))) float f32x4;

// fp32 -> bf16 RNE via compiler path (lowers to v_cvt_pk_bf16_f32 when paired)
static __device__ __forceinline__ short f2bf(float f) {
    __hip_bfloat16 h = __float2bfloat16(f);
    union { __hip_bfloat16 h; short s; } c; c.h = h; return c.s;
}

// pack two fp32 -> one dword of 2x bf16 (v_cvt_pk_bf16_f32)
static __device__ __forceinline__ unsigned pkbf2(float a, float b) {
    __hip_bfloat162 h = __float22bfloat162_rn(make_float2(a, b));
    union { __hip_bfloat162 h; unsigned u; } c; c.h = h; return c.u;
}

static __device__ __forceinline__ void gload16(const void* g, void* l) {
    __builtin_amdgcn_global_load_lds(
        (const __attribute__((address_space(1))) unsigned int*)g,
        (__attribute__((address_space(3))) unsigned int*)l, 16, 0, 0);
}

// ---- fp32 -> bf16 conversion of all tensors (grid-stride, 8 elems/thread/iter)
__global__ __launch_bounds__(256) void cvt6(
    const float* __restrict__ q, const float* __restrict__ k,
    const float* __restrict__ v, const float* __restrict__ wq,
    const float* __restrict__ wo, const float* __restrict__ wk,
    const float* __restrict__ wv,
    short* __restrict__ qo, short* __restrict__ ko, short* __restrict__ vo,
    short* __restrict__ wqo, short* __restrict__ woo, short* __restrict__ wko,
    short* __restrict__ wvo)
{
    const int NB = (MROWS * D_MODEL) / 8;
    const int NW = (D_MODEL * D_MODEL) / 8;
    const int NS = (DK * D_MODEL) / 8;
    const int total = 3 * NB + 2 * NW + 2 * NS;
    for (int g = blockIdx.x * 256 + threadIdx.x; g < total; g += gridDim.x * 256) {
        const float* s; short* d; int x = g;
        if (x < NB)            { s = q;  d = qo;  }
        else if ((x -= NB) < NB) { s = k;  d = ko;  }
        else if ((x -= NB) < NB) { s = v;  d = vo;  }
        else if ((x -= NB) < NW) { s = wq; d = wqo; }
        else if ((x -= NW) < NW) { s = wo; d = woo; }
        else if ((x -= NW) < NS) { s = wk; d = wko; }
        else                     { x -= NS; s = wv; d = wvo; }
        float4 a = ((const float4*)s)[x * 2];
        float4 b = ((const float4*)s)[x * 2 + 1];
        uint4 hv;
        hv.x = pkbf2(a.x, a.y); hv.y = pkbf2(a.z, a.w);
        hv.z = pkbf2(b.x, b.y); hv.w = pkbf2(b.z, b.w);
        ((uint4*)d)[x] = hv;
    }
}

// C[M,N] = (A[M,K] @ W[N,K]^T + bias[N]) * outmult, all-bf16 in, gload_lds staging.
// MODE 0: bf16 out. MODE 1: fp32 out. MODE 2: blockIdx.y selects K-proj/V-proj(T).
template<int MODE, int BM, int BN>
__global__ __launch_bounds__(256) void gemm97(
    const short* __restrict__ A, const short* __restrict__ W,
    const float* __restrict__ bias, void* __restrict__ Cp,
    const short* __restrict__ A2, const short* __restrict__ W2,
    const float* __restrict__ bias2, void* __restrict__ Cp2,
    int M, int N, int K, float outmult)
{
    constexpr int MI = BM / 32;
    constexpr int NI = BN / 32;
    constexpr int ACH = BM / 32;
    constexpr int WCH = BN / 32;
    __shared__ short As[BM * 64];
    __shared__ short Ws[BN * 64];

    int sel = 0;
    if (MODE == 2) {
        sel = blockIdx.y;
        if (sel) { A = A2; W = W2; bias = bias2; Cp = Cp2; }
    }
    const int bm = blockIdx.x * BM;
    const int bn = (MODE == 2) ? 0 : blockIdx.y * BN;
    const int tid = threadIdx.x;
    const int l = tid & 63, w = tid >> 6;
    const int lr = l & 15, lg = l >> 4;
    const int wm = (w >> 1) * (BM / 2), wn = (w & 1) * (BN / 2);

    f32x4 acc[MI][NI];
    #pragma unroll
    for (int mi = 0; mi < MI; mi++)
        #pragma unroll
        for (int ni = 0; ni < NI; ni++)
            acc[mi][ni] = (f32x4){0.f, 0.f, 0.f, 0.f};

    const int srow = l >> 3;
    const int scol = (l & 7) * 8;

    for (int k0 = 0; k0 < K; k0 += 64) {
        __syncthreads();
        #pragma unroll
        for (int i = 0; i < ACH; i++) {
            int c = w * ACH + i;
            gload16(A + (size_t)(bm + 8 * c + srow) * K + k0 + scol, As + c * 512);
        }
        #pragma unroll
        for (int i = 0; i < WCH; i++) {
            int c = w * WCH + i;
            gload16(W + (size_t)(bn + 8 * c + srow) * K + k0 + scol, Ws + c * 512);
        }
        __syncthreads();
        #pragma unroll
        for (int ks = 0; ks < 2; ks++) {
            bf16x8 af[MI], bf[NI];
            #pragma unroll
            for (int mi = 0; mi < MI; mi++)
                af[mi] = *(const bf16x8*)&As[(wm + mi * 16 + lr) * 64 + ks * 32 + 8 * lg];
            #pragma unroll
            for (int ni = 0; ni < NI; ni++)
                bf[ni] = *(const bf16x8*)&Ws[(wn + ni * 16 + lr) * 64 + ks * 32 + 8 * lg];
            #pragma unroll
            for (int mi = 0; mi < MI; mi++)
                #pragma unroll
                for (int ni = 0; ni < NI; ni++)
                    acc[mi][ni] = __builtin_amdgcn_mfma_f32_16x16x32_bf16(
                        af[mi], bf[ni], acc[mi][ni], 0, 0, 0);
        }
    }

    #pragma unroll
    for (int ni = 0; ni < NI; ni++) {
        int col = bn + wn + ni * 16 + lr;
        float bv = bias[col];
        #pragma unroll
        for (int mi = 0; mi < MI; mi++) {
            #pragma unroll
            for (int r = 0; r < 4; r++) {
                int row = bm + wm + mi * 16 + lg * 4 + r;
                float val = (acc[mi][ni][r] + bv) * outmult;
                if (MODE == 0) {
                    ((short*)Cp)[(size_t)row * N + col] = f2bf(val);
                } else if (MODE == 1) {
                    ((float*)Cp)[(size_t)row * N + col] = val;
                } else {
                    if (sel == 0) {
                        ((short*)Cp)[(size_t)row * DK + col] = f2bf(val);
                    } else {
                        int bi = row >> 11, si = row & (SEQ - 1);
                        ((short*)Cp)[((size_t)bi * DK + col) * SEQ + si] = f2bf(val);
                    }
                }
            }
        }
    }
}

// Flash MQA attention: block-shared double-buffered K/V in LDS.
// 4 waves x 32 q-rows = 128 q-rows/block; grid (SEQ/128, H, B) = 512 blocks.
// Swapped operands: S^T = K.Q^T, O^T = V^T.P^T (per-lane softmax stats).
// K tile [64 keys][64 dk], V^T tile [64 dk][64 keys], both XOR-swizzled
// (byte ^= (row&7)<<4) via pre-swizzled GLOBAL source + linear gload_lds dest.
// qb PRE-SCALED by log2(e)/8  -> softmax runs in exp2 domain (exact).
// Defer-max (T13): skip corr/rescale while tile max <= m + 8 (P bounded by 2^8).
__global__ __launch_bounds__(256, 3) void mqa_attn_lds(
    const short* __restrict__ qb, const short* __restrict__ kb,
    const short* __restrict__ vt, short* __restrict__ ob)
{
    __shared__ char KsB[2][64 * 128];
    __shared__ char VsB[2][64 * 128];
    __shared__ char Ps[4][32 * 128];
    const int h = blockIdx.y, b = blockIdx.z;
    const int tid = threadIdx.x;
    const int l = tid & 63, w = tid >> 6;
    const int lr = l & 15, lg = l >> 4;
    const int q0 = blockIdx.x * 128 + w * 32;
    char* myPs = Ps[w];

    // Q fragments (registers, whole kernel)
    bf16x8 qf[2][2];
    #pragma unroll
    for (int qt = 0; qt < 2; qt++)
        #pragma unroll
        for (int kk = 0; kk < 2; kk++)
            qf[qt][kk] = *(const bf16x8*)(
                qb + (size_t)(b * SEQ + q0 + qt * 16 + lr) * D_MODEL + h * DK + kk * 32 + 8 * lg);

    // staging source indices (per-lane, loop-invariant parts)
    int srow[2], scol[2];
    #pragma unroll
    for (int i = 0; i < 2; i++) {
        int s = i * 256 + w * 64 + l;
        srow[i] = s >> 3;
        int cb = (s & 7) * 16;
        scol[i] = (cb ^ ((srow[i] & 7) << 4)) >> 1;   // short offset within row
    }

    f32x4 o[4][2];
    #pragma unroll
    for (int dt = 0; dt < 4; dt++)
        #pragma unroll
        for (int qt = 0; qt < 2; qt++)
            o[dt][qt] = (f32x4){0.f, 0.f, 0.f, 0.f};
    float m_i[2] = {-1e30f, -1e30f};
    float l_i[2] = {0.f, 0.f};

    // prologue: stage tile 0 into buffer 0
    #pragma unroll
    for (int i = 0; i < 2; i++) {
        gload16(kb + (size_t)(b * SEQ + 0 + srow[i]) * DK + scol[i],
                KsB[0] + (i * 256 + w * 64) * 16);
        gload16(vt + (size_t)(b * DK + srow[i]) * SEQ + 0 + scol[i],
                VsB[0] + (i * 256 + w * 64) * 16);
    }

    for (int t = 0; t < SEQ / 64; t++) {
        const int cur = t & 1;
        const int kt = t * 64;
        __syncthreads();   // drains this thread's tile-t loads; all waves' data in LDS
        if (t + 1 < SEQ / 64) {
            const int ktn = kt + 64;
            #pragma unroll
            for (int i = 0; i < 2; i++) {
                gload16(kb + (size_t)(b * SEQ + ktn + srow[i]) * DK + scol[i],
                        KsB[cur ^ 1] + (i * 256 + w * 64) * 16);
                gload16(vt + (size_t)(b * DK + srow[i]) * SEQ + ktn + scol[i],
                        VsB[cur ^ 1] + (i * 256 + w * 64) * 16);
            }
        }
        const char* Kc = KsB[cur];
        const char* Vc = VsB[cur];

        // ---- S^T = K . Q^T ----
        f32x4 s[2][4];
        #pragma unroll
        for (int qt = 0; qt < 2; qt++)
            #pragma unroll
            for (int j = 0; j < 4; j++) s[qt][j] = (f32x4){0.f, 0.f, 0.f, 0.f};
        #pragma unroll
        for (int kk = 0; kk < 2; kk++) {
            bf16x8 kf[4];
            #pragma unroll
            for (int j = 0; j < 4; j++) {
                int row = j * 16 + lr;
                kf[j] = *(const bf16x8*)(Kc + row * 128 + ((kk * 64 + 16 * lg) ^ ((row & 7) << 4)));
            }
            __builtin_amdgcn_s_setprio(1);
            #pragma unroll
            for (int qt = 0; qt < 2; qt++)
                #pragma unroll
                for (int j = 0; j < 4; j++)
                    s[qt][j] = __builtin_amdgcn_mfma_f32_16x16x32_bf16(
                        kf[j], qf[qt][kk], s[qt][j], 0, 0, 0);
            __builtin_amdgcn_s_setprio(0);
        }

        // ---- per-lane online softmax (exp2 domain) with defer-max ----
        float corr[2]; int resc[2];
        #pragma unroll
        for (int qt = 0; qt < 2; qt++) {
            // max3-friendly tree over 16 in-register scores
            float mA = fmaxf(fmaxf(s[qt][0][0], s[qt][0][1]), s[qt][0][2]);
            float mB = fmaxf(fmaxf(s[qt][0][3], s[qt][1][0]), s[qt][1][1]);
            float mC = fmaxf(fmaxf(s[qt][1][2], s[qt][1][3]), s[qt][2][0]);
            float mD = fmaxf(fmaxf(s[qt][2][1], s[qt][2][2]), s[qt][2][3]);
            float mE = fmaxf(fmaxf(s[qt][3][0], s[qt][3][1]), s[qt][3][2]);
            float mx = fmaxf(fmaxf(fmaxf(mA, mB), mC),
                             fmaxf(fmaxf(mD, mE), s[qt][3][3]));
            mx = fmaxf(mx, __shfl_xor(mx, 16));
            mx = fmaxf(mx, __shfl_xor(mx, 32));

            resc[qt] = __any(mx > m_i[qt] + 8.0f);   // wave-uniform
            if (resc[qt]) {
                float mn = fmaxf(m_i[qt], mx);
                corr[qt] = __builtin_amdgcn_exp2f(m_i[qt] - mn);
                m_i[qt] = mn;
            } else {
                corr[qt] = 1.0f;
            }
            const float mnv = m_i[qt];

            float rs = 0.f;
            const int row = qt * 16 + lr;
            char* base = myPs + row * 128;
            const int sw = (row & 7) << 4;
            #pragma unroll
            for (int j = 0; j < 4; j++) {
                float p0 = __builtin_amdgcn_exp2f(s[qt][j][0] - mnv);
                float p1 = __builtin_amdgcn_exp2f(s[qt][j][1] - mnv);
                float p2 = __builtin_amdgcn_exp2f(s[qt][j][2] - mnv);
                float p3 = __builtin_amdgcn_exp2f(s[qt][j][3] - mnv);
                rs += (p0 + p1) + (p2 + p3);
                uint2 pk;
                pk.x = pkbf2(p0, p1);
                pk.y = pkbf2(p2, p3);
                *(uint2*)(base + ((j * 32 + lg * 8) ^ sw)) = pk;
            }
            rs += __shfl_xor(rs, 16);
            rs += __shfl_xor(rs, 32);
            l_i[qt] = l_i[qt] * corr[qt] + rs;
        }
        // O-rescale only on the (rare) tiles that moved the running max
        #pragma unroll
        for (int qt = 0; qt < 2; qt++)
            if (resc[qt]) {
                #pragma unroll
                for (int dt = 0; dt < 4; dt++)
                    o[dt][qt] *= corr[qt];
            }

        // ---- O^T += V^T . P^T ----
        #pragma unroll
        for (int kk = 0; kk < 2; kk++) {
            bf16x8 vf[4], pf[2];
            #pragma unroll
            for (int dt = 0; dt < 4; dt++) {
                int row = dt * 16 + lr;
                vf[dt] = *(const bf16x8*)(Vc + row * 128 + ((kk * 64 + 16 * lg) ^ ((row & 7) << 4)));
            }
            #pragma unroll
            for (int qt = 0; qt < 2; qt++) {
                int row = qt * 16 + lr;
                pf[qt] = *(bf16x8*)(myPs + row * 128 + ((kk * 64 + 16 * lg) ^ ((row & 7) << 4)));
            }
            __builtin_amdgcn_s_setprio(1);
            #pragma unroll
            for (int dt = 0; dt < 4; dt++)
                #pragma unroll
                for (int qt = 0; qt < 2; qt++)
                    o[dt][qt] = __builtin_amdgcn_mfma_f32_16x16x32_bf16(
                        vf[dt], pf[qt], o[dt][qt], 0, 0, 0);
            __builtin_amdgcn_s_setprio(0);
        }
    }

    // ---- epilogue: per-lane normalize, packed 8B stores ----
    #pragma unroll
    for (int qt = 0; qt < 2; qt++) {
        float inv = 1.0f / l_i[qt];
        size_t grow = (size_t)(b * SEQ + q0 + qt * 16 + lr);
        #pragma unroll
        for (int dt = 0; dt < 4; dt++) {
            uint2 pk;
            pk.x = pkbf2(o[dt][qt][0] * inv, o[dt][qt][1] * inv);
            pk.y = pkbf2(o[dt][qt][2] * inv, o[dt][qt][3] * inv);
            *(uint2*)(ob + grow * D_MODEL + h * DK + dt * 16 + lg * 4) = pk;
        }
    }
}

extern "C" void kernel_launch(void* const* d_in, const int* in_sizes, int n_in,
                              void* d_out, int out_size, void* d_ws, size_t ws_size,
                              hipStream_t stream) {
    const float* Q   = (const float*)d_in[0];
    const float* K   = (const float*)d_in[1];
    const float* V   = (const float*)d_in[2];
    const float* W_Q = (const float*)d_in[3];
    const float* b_Q = (const float*)d_in[4];
    const float* W_K = (const float*)d_in[5];
    const float* b_K = (const float*)d_in[6];
    const float* W_V = (const float*)d_in[7];
    const float* b_V = (const float*)d_in[8];
    const float* W_O = (const float*)d_in[9];
    const float* b_O = (const float*)d_in[10];
    float* out = (float*)d_out;

    short* Qb  = (short*)d_ws;
    short* Kb  = Qb  + (size_t)MROWS * D_MODEL;
    short* Vb  = Kb  + (size_t)MROWS * D_MODEL;
    short* WQb = Vb  + (size_t)MROWS * D_MODEL;
    short* WKb = WQb + (size_t)D_MODEL * D_MODEL;
    short* WVb = WKb + (size_t)DK * D_MODEL;
    short* WOb = WVb + (size_t)DK * D_MODEL;
    short* qb  = WOb + (size_t)D_MODEL * D_MODEL;
    short* kb  = qb  + (size_t)MROWS * D_MODEL;
    short* vt  = kb  + (size_t)MROWS * DK;
    short* aws = vt  + (size_t)MROWS * DK;

    cvt6<<<2048, 256, 0, stream>>>(Q, K, V, W_Q, W_O, W_K, W_V,
                                   Qb, Kb, Vb, WQb, WOb, WKb, WVb);

    // Q projection, pre-scaled by log2(e)/sqrt(dk) (exp2-domain softmax)
    gemm97<0, 64, 128><<<dim3(MROWS / 64, D_MODEL / 128), 256, 0, stream>>>(
        Qb, WQb, b_Q, qb, nullptr, nullptr, nullptr, nullptr,
        MROWS, D_MODEL, D_MODEL, QSCALE);
    // K + V projections fused by blockIdx.y
    gemm97<2, 64, 64><<<dim3(MROWS / 64, 2), 256, 0, stream>>>(
        Kb, WKb, b_K, kb, Vb, WVb, b_V, vt, MROWS, DK, D_MODEL, 1.0f);
    // attention (block-shared LDS K/V, double-buffered)
    mqa_attn_lds<<<dim3(SEQ / 128, NUM_HEADS, BATCH), 256, 0, stream>>>(
        qb, kb, vt, aws);
    // output projection (fp32 out)
    gemm97<1, 64, 128><<<dim3(MROWS / 64, D_MODEL / 128), 256, 0, stream>>>(
        aws, WOb, b_O, out, nullptr, nullptr, nullptr, nullptr,
        MROWS, D_MODEL, D_MODEL, 1.0f);
}

// Round 2
// 130.887 us; speedup vs baseline: 1.0792x; 1.0126x over previous
//
#include <hip/hip_runtime.h>
#include <hip/hip_bf16.h>
#include <math.h>

#define D_MODEL 1024
#define NUM_HEADS 16
#define DK 64
#define BATCH 2
#define SEQ 2048
#define MROWS (BATCH * SEQ)   // 4096

// Q projection pre-scale: 1/sqrt(dk) * log2(e)  -> scores arrive in log2 domain
#define QSCALE (0.125f * 1.4426950408889634f)

typedef __attribute__((ext_vector_type(8))) short bf16x8;
typedef __attribute__((ext_vector_type(4))) float f32x4;

// fp32 -> bf16 RNE via compiler path (lowers to v_cvt_pk_bf16_f32 when paired)
static __device__ __forceinline__ short f2bf(float f) {
    __hip_bfloat16 h = __float2bfloat16(f);
    union { __hip_bfloat16 h; short s; } c; c.h = h; return c.s;
}

// pack two fp32 -> one dword of 2x bf16 (v_cvt_pk_bf16_f32)
static __device__ __forceinline__ unsigned pkbf2(float a, float b) {
    __hip_bfloat162 h = __float22bfloat162_rn(make_float2(a, b));
    union { __hip_bfloat162 h; unsigned u; } c; c.h = h; return c.u;
}

static __device__ __forceinline__ void gload16(const void* g, void* l) {
    __builtin_amdgcn_global_load_lds(
        (const __attribute__((address_space(1))) unsigned int*)g,
        (__attribute__((address_space(3))) unsigned int*)l, 16, 0, 0);
}

// ---- fp32 -> bf16 conversion of all tensors (grid-stride, 8 elems/thread/iter)
__global__ __launch_bounds__(256) void cvt6(
    const float* __restrict__ q, const float* __restrict__ k,
    const float* __restrict__ v, const float* __restrict__ wq,
    const float* __restrict__ wo, const float* __restrict__ wk,
    const float* __restrict__ wv,
    short* __restrict__ qo, short* __restrict__ ko, short* __restrict__ vo,
    short* __restrict__ wqo, short* __restrict__ woo, short* __restrict__ wko,
    short* __restrict__ wvo)
{
    const int NB = (MROWS * D_MODEL) / 8;
    const int NW = (D_MODEL * D_MODEL) / 8;
    const int NS = (DK * D_MODEL) / 8;
    const int total = 3 * NB + 2 * NW + 2 * NS;
    for (int g = blockIdx.x * 256 + threadIdx.x; g < total; g += gridDim.x * 256) {
        const float* s; short* d; int x = g;
        if (x < NB)            { s = q;  d = qo;  }
        else if ((x -= NB) < NB) { s = k;  d = ko;  }
        else if ((x -= NB) < NB) { s = v;  d = vo;  }
        else if ((x -= NB) < NW) { s = wq; d = wqo; }
        else if ((x -= NW) < NW) { s = wo; d = woo; }
        else if ((x -= NW) < NS) { s = wk; d = wko; }
        else                     { x -= NS; s = wv; d = wvo; }
        float4 a = ((const float4*)s)[x * 2];
        float4 b = ((const float4*)s)[x * 2 + 1];
        uint4 hv;
        hv.x = pkbf2(a.x, a.y); hv.y = pkbf2(a.z, a.w);
        hv.z = pkbf2(b.x, b.y); hv.w = pkbf2(b.z, b.w);
        ((uint4*)d)[x] = hv;
    }
}

// C[M,N] = (A[M,K] @ W[N,K]^T + bias[N]) * outmult, all-bf16 in, gload_lds staging.
// MODE 0: bf16 out. MODE 1: fp32 out. MODE 2: blockIdx.y selects K-proj/V-proj(T).
template<int MODE, int BM, int BN>
__global__ __launch_bounds__(256) void gemm97(
    const short* __restrict__ A, const short* __restrict__ W,
    const float* __restrict__ bias, void* __restrict__ Cp,
    const short* __restrict__ A2, const short* __restrict__ W2,
    const float* __restrict__ bias2, void* __restrict__ Cp2,
    int M, int N, int K, float outmult)
{
    constexpr int MI = BM / 32;
    constexpr int NI = BN / 32;
    constexpr int ACH = BM / 32;
    constexpr int WCH = BN / 32;
    __shared__ short As[BM * 64];
    __shared__ short Ws[BN * 64];

    int sel = 0;
    if (MODE == 2) {
        sel = blockIdx.y;
        if (sel) { A = A2; W = W2; bias = bias2; Cp = Cp2; }
    }
    const int bm = blockIdx.x * BM;
    const int bn = (MODE == 2) ? 0 : blockIdx.y * BN;
    const int tid = threadIdx.x;
    const int l = tid & 63, w = tid >> 6;
    const int lr = l & 15, lg = l >> 4;
    const int wm = (w >> 1) * (BM / 2), wn = (w & 1) * (BN / 2);

    f32x4 acc[MI][NI];
    #pragma unroll
    for (int mi = 0; mi < MI; mi++)
        #pragma unroll
        for (int ni = 0; ni < NI; ni++)
            acc[mi][ni] = (f32x4){0.f, 0.f, 0.f, 0.f};

    const int srow = l >> 3;
    const int scol = (l & 7) * 8;

    for (int k0 = 0; k0 < K; k0 += 64) {
        __syncthreads();
        #pragma unroll
        for (int i = 0; i < ACH; i++) {
            int c = w * ACH + i;
            gload16(A + (size_t)(bm + 8 * c + srow) * K + k0 + scol, As + c * 512);
        }
        #pragma unroll
        for (int i = 0; i < WCH; i++) {
            int c = w * WCH + i;
            gload16(W + (size_t)(bn + 8 * c + srow) * K + k0 + scol, Ws + c * 512);
        }
        __syncthreads();
        #pragma unroll
        for (int ks = 0; ks < 2; ks++) {
            bf16x8 af[MI], bf[NI];
            #pragma unroll
            for (int mi = 0; mi < MI; mi++)
                af[mi] = *(const bf16x8*)&As[(wm + mi * 16 + lr) * 64 + ks * 32 + 8 * lg];
            #pragma unroll
            for (int ni = 0; ni < NI; ni++)
                bf[ni] = *(const bf16x8*)&Ws[(wn + ni * 16 + lr) * 64 + ks * 32 + 8 * lg];
            #pragma unroll
            for (int mi = 0; mi < MI; mi++)
                #pragma unroll
                for (int ni = 0; ni < NI; ni++)
                    acc[mi][ni] = __builtin_amdgcn_mfma_f32_16x16x32_bf16(
                        af[mi], bf[ni], acc[mi][ni], 0, 0, 0);
        }
    }

    #pragma unroll
    for (int ni = 0; ni < NI; ni++) {
        int col = bn + wn + ni * 16 + lr;
        float bv = bias[col];
        #pragma unroll
        for (int mi = 0; mi < MI; mi++) {
            #pragma unroll
            for (int r = 0; r < 4; r++) {
                int row = bm + wm + mi * 16 + lg * 4 + r;
                float val = (acc[mi][ni][r] + bv) * outmult;
                if (MODE == 0) {
                    ((short*)Cp)[(size_t)row * N + col] = f2bf(val);
                } else if (MODE == 1) {
                    ((float*)Cp)[(size_t)row * N + col] = val;
                } else {
                    if (sel == 0) {
                        ((short*)Cp)[(size_t)row * DK + col] = f2bf(val);
                    } else {
                        int bi = row >> 11, si = row & (SEQ - 1);
                        ((short*)Cp)[((size_t)bi * DK + col) * SEQ + si] = f2bf(val);
                    }
                }
            }
        }
    }
}

// Flash MQA attention: block-shared double-buffered K/V in LDS.
// RESTRUCTURED for occupancy: 4 waves x 16 q-rows = 64 q-rows/block;
// grid (SEQ/64, H, B) = 1024 blocks; LDS 40KB -> 4 blocks/CU = 16 waves/CU.
// Swapped operands: S^T = K.Q^T, O^T = V^T.P^T (per-lane softmax stats).
// K tile [64 keys][64 dk], V^T tile [64 dk][64 keys], both XOR-swizzled
// (byte ^= (row&7)<<4) via pre-swizzled GLOBAL source + linear gload_lds dest.
// qb PRE-SCALED by log2(e)/8  -> softmax runs in exp2 domain (exact).
// Lazy max: per-lane max only on common path; cross-lane reduce + rescale only
// when __any(lane_max > m + 8) (first tile per row in practice). Per-lane
// partial l, reduced once in the epilogue -> zero cross-lane ops per tile.
__global__ __launch_bounds__(256, 4) void mqa_attn_lds(
    const short* __restrict__ qb, const short* __restrict__ kb,
    const short* __restrict__ vt, short* __restrict__ ob)
{
    __shared__ char KsB[2][64 * 128];
    __shared__ char VsB[2][64 * 128];
    __shared__ char Ps[4][16 * 128];
    const int h = blockIdx.y, b = blockIdx.z;
    const int tid = threadIdx.x;
    const int l = tid & 63, w = tid >> 6;
    const int lr = l & 15, lg = l >> 4;
    const int q0 = blockIdx.x * 64 + w * 16;
    char* myPs = Ps[w];

    // Q fragments (registers, whole kernel)
    bf16x8 qf[2];
    #pragma unroll
    for (int kk = 0; kk < 2; kk++)
        qf[kk] = *(const bf16x8*)(
            qb + (size_t)(b * SEQ + q0 + lr) * D_MODEL + h * DK + kk * 32 + 8 * lg);

    // staging source indices (per-lane, loop-invariant parts)
    int srow[2], scol[2];
    #pragma unroll
    for (int i = 0; i < 2; i++) {
        int s = i * 256 + w * 64 + l;
        srow[i] = s >> 3;
        int cb = (s & 7) * 16;
        scol[i] = (cb ^ ((srow[i] & 7) << 4)) >> 1;   // short offset within row
    }

    f32x4 o[4];
    #pragma unroll
    for (int dt = 0; dt < 4; dt++)
        o[dt] = (f32x4){0.f, 0.f, 0.f, 0.f};
    float m_i = -1e30f;   // row-uniform running max (log2 domain)
    float l_l = 0.f;      // PER-LANE partial sum; reduced in epilogue

    // prologue: stage tile 0 into buffer 0
    #pragma unroll
    for (int i = 0; i < 2; i++) {
        gload16(kb + (size_t)(b * SEQ + 0 + srow[i]) * DK + scol[i],
                KsB[0] + (i * 256 + w * 64) * 16);
        gload16(vt + (size_t)(b * DK + srow[i]) * SEQ + 0 + scol[i],
                VsB[0] + (i * 256 + w * 64) * 16);
    }

    for (int t = 0; t < SEQ / 64; t++) {
        const int cur = t & 1;
        const int kt = t * 64;
        __syncthreads();   // drains this thread's tile-t loads; all waves' data in LDS
        if (t + 1 < SEQ / 64) {
            const int ktn = kt + 64;
            #pragma unroll
            for (int i = 0; i < 2; i++) {
                gload16(kb + (size_t)(b * SEQ + ktn + srow[i]) * DK + scol[i],
                        KsB[cur ^ 1] + (i * 256 + w * 64) * 16);
                gload16(vt + (size_t)(b * DK + srow[i]) * SEQ + ktn + scol[i],
                        VsB[cur ^ 1] + (i * 256 + w * 64) * 16);
            }
        }
        const char* Kc = KsB[cur];
        const char* Vc = VsB[cur];

        // ---- S^T = K . Q^T ----  (16 q-rows x 64 keys per wave)
        f32x4 s[4];
        #pragma unroll
        for (int j = 0; j < 4; j++) s[j] = (f32x4){0.f, 0.f, 0.f, 0.f};
        #pragma unroll
        for (int kk = 0; kk < 2; kk++) {
            bf16x8 kf[4];
            #pragma unroll
            for (int j = 0; j < 4; j++) {
                int row = j * 16 + lr;
                kf[j] = *(const bf16x8*)(Kc + row * 128 + ((kk * 64 + 16 * lg) ^ ((row & 7) << 4)));
            }
            __builtin_amdgcn_s_setprio(1);
            #pragma unroll
            for (int j = 0; j < 4; j++)
                s[j] = __builtin_amdgcn_mfma_f32_16x16x32_bf16(
                    kf[j], qf[kk], s[j], 0, 0, 0);
            __builtin_amdgcn_s_setprio(0);
        }

        // ---- per-lane online softmax (exp2 domain), lazy cross-lane max ----
        {
            float mA = fmaxf(fmaxf(s[0][0], s[0][1]), s[0][2]);
            float mB = fmaxf(fmaxf(s[0][3], s[1][0]), s[1][1]);
            float mC = fmaxf(fmaxf(s[1][2], s[1][3]), s[2][0]);
            float mD = fmaxf(fmaxf(s[2][1], s[2][2]), s[2][3]);
            float mE = fmaxf(fmaxf(s[3][0], s[3][1]), s[3][2]);
            float mx = fmaxf(fmaxf(fmaxf(mA, mB), mC),
                             fmaxf(fmaxf(mD, mE), s[3][3]));

            if (__any(mx > m_i + 8.0f)) {   // wave-uniform, rare (first tile)
                float mxf = fmaxf(mx, __shfl_xor(mx, 16));
                mxf = fmaxf(mxf, __shfl_xor(mxf, 32));
                float mn = fmaxf(m_i, mxf);
                float corr = __builtin_amdgcn_exp2f(m_i - mn);
                m_i = mn;
                l_l *= corr;
                #pragma unroll
                for (int dt = 0; dt < 4; dt++)
                    o[dt] *= corr;
            }
            const float mnv = m_i;

            float rs = 0.f;
            char* base = myPs + lr * 128;
            const int sw = (lr & 7) << 4;
            #pragma unroll
            for (int j = 0; j < 4; j++) {
                float p0 = __builtin_amdgcn_exp2f(s[j][0] - mnv);
                float p1 = __builtin_amdgcn_exp2f(s[j][1] - mnv);
                float p2 = __builtin_amdgcn_exp2f(s[j][2] - mnv);
                float p3 = __builtin_amdgcn_exp2f(s[j][3] - mnv);
                rs += (p0 + p1) + (p2 + p3);
                uint2 pk;
                pk.x = pkbf2(p0, p1);
                pk.y = pkbf2(p2, p3);
                *(uint2*)(base + ((j * 32 + lg * 8) ^ sw)) = pk;
            }
            l_l += rs;   // per-lane partial; no cross-lane reduce here
        }

        // ---- O^T += V^T . P^T ----
        #pragma unroll
        for (int kk = 0; kk < 2; kk++) {
            bf16x8 vf[4], pf;
            #pragma unroll
            for (int dt = 0; dt < 4; dt++) {
                int row = dt * 16 + lr;
                vf[dt] = *(const bf16x8*)(Vc + row * 128 + ((kk * 64 + 16 * lg) ^ ((row & 7) << 4)));
            }
            pf = *(bf16x8*)(myPs + lr * 128 + ((kk * 64 + 16 * lg) ^ ((lr & 7) << 4)));
            __builtin_amdgcn_s_setprio(1);
            #pragma unroll
            for (int dt = 0; dt < 4; dt++)
                o[dt] = __builtin_amdgcn_mfma_f32_16x16x32_bf16(
                    vf[dt], pf, o[dt], 0, 0, 0);
            __builtin_amdgcn_s_setprio(0);
        }
    }

    // ---- epilogue: reduce per-lane l across the 4 lane-groups, normalize ----
    float lt = l_l;
    lt += __shfl_xor(lt, 16);
    lt += __shfl_xor(lt, 32);
    float inv = 1.0f / lt;
    size_t grow = (size_t)(b * SEQ + q0 + lr);
    #pragma unroll
    for (int dt = 0; dt < 4; dt++) {
        uint2 pk;
        pk.x = pkbf2(o[dt][0] * inv, o[dt][1] * inv);
        pk.y = pkbf2(o[dt][2] * inv, o[dt][3] * inv);
        *(uint2*)(ob + grow * D_MODEL + h * DK + dt * 16 + lg * 4) = pk;
    }
}

extern "C" void kernel_launch(void* const* d_in, const int* in_sizes, int n_in,
                              void* d_out, int out_size, void* d_ws, size_t ws_size,
                              hipStream_t stream) {
    const float* Q   = (const float*)d_in[0];
    const float* K   = (const float*)d_in[1];
    const float* V   = (const float*)d_in[2];
    const float* W_Q = (const float*)d_in[3];
    const float* b_Q = (const float*)d_in[4];
    const float* W_K = (const float*)d_in[5];
    const float* b_K = (const float*)d_in[6];
    const float* W_V = (const float*)d_in[7];
    const float* b_V = (const float*)d_in[8];
    const float* W_O = (const float*)d_in[9];
    const float* b_O = (const float*)d_in[10];
    float* out = (float*)d_out;

    short* Qb  = (short*)d_ws;
    short* Kb  = Qb  + (size_t)MROWS * D_MODEL;
    short* Vb  = Kb  + (size_t)MROWS * D_MODEL;
    short* WQb = Vb  + (size_t)MROWS * D_MODEL;
    short* WKb = WQb + (size_t)D_MODEL * D_MODEL;
    short* WVb = WKb + (size_t)DK * D_MODEL;
    short* WOb = WVb + (size_t)DK * D_MODEL;
    short* qb  = WOb + (size_t)D_MODEL * D_MODEL;
    short* kb  = qb  + (size_t)MROWS * D_MODEL;
    short* vt  = kb  + (size_t)MROWS * DK;
    short* aws = vt  + (size_t)MROWS * DK;

    cvt6<<<2048, 256, 0, stream>>>(Q, K, V, W_Q, W_O, W_K, W_V,
                                   Qb, Kb, Vb, WQb, WOb, WKb, WVb);

    // Q projection, pre-scaled by log2(e)/sqrt(dk) (exp2-domain softmax)
    gemm97<0, 64, 128><<<dim3(MROWS / 64, D_MODEL / 128), 256, 0, stream>>>(
        Qb, WQb, b_Q, qb, nullptr, nullptr, nullptr, nullptr,
        MROWS, D_MODEL, D_MODEL, QSCALE);
    // K + V projections fused by blockIdx.y
    gemm97<2, 64, 64><<<dim3(MROWS / 64, 2), 256, 0, stream>>>(
        Kb, WKb, b_K, kb, Vb, WVb, b_V, vt, MROWS, DK, D_MODEL, 1.0f);
    // attention: 64 q-rows/block, 1024 blocks, 4 blocks/CU (40KB LDS)
    mqa_attn_lds<<<dim3(SEQ / 64, NUM_HEADS, BATCH), 256, 0, stream>>>(
        qb, kb, vt, aws);
    // output projection (fp32 out)
    gemm97<1, 64, 128><<<dim3(MROWS / 64, D_MODEL / 128), 256, 0, stream>>>(
        aws, WOb, b_O, out, nullptr, nullptr, nullptr, nullptr,
        MROWS, D_MODEL, D_MODEL, 1.0f);
}

// Round 3
// 126.454 us; speedup vs baseline: 1.1170x; 1.0351x over previous
//
#include <hip/hip_runtime.h>
#include <hip/hip_bf16.h>
#include <math.h>

#define D_MODEL 1024
#define NUM_HEADS 16
#define DK 64
#define BATCH 2
#define SEQ 2048
#define MROWS (BATCH * SEQ)   // 4096

// Q projection pre-scale: 1/sqrt(dk) * log2(e)  -> scores arrive in log2 domain
#define QSCALE (0.125f * 1.4426950408889634f)

typedef __attribute__((ext_vector_type(8))) short bf16x8;
typedef __attribute__((ext_vector_type(4))) float f32x4;

// fp32 -> bf16 RNE via compiler path (lowers to v_cvt_pk_bf16_f32 when paired)
static __device__ __forceinline__ short f2bf(float f) {
    __hip_bfloat16 h = __float2bfloat16(f);
    union { __hip_bfloat16 h; short s; } c; c.h = h; return c.s;
}

// pack two fp32 -> one dword of 2x bf16 (v_cvt_pk_bf16_f32)
static __device__ __forceinline__ unsigned pkbf2(float a, float b) {
    __hip_bfloat162 h = __float22bfloat162_rn(make_float2(a, b));
    union { __hip_bfloat162 h; unsigned u; } c; c.h = h; return c.u;
}

static __device__ __forceinline__ void gload16(const void* g, void* l) {
    __builtin_amdgcn_global_load_lds(
        (const __attribute__((address_space(1))) unsigned int*)g,
        (__attribute__((address_space(3))) unsigned int*)l, 16, 0, 0);
}

// ---- fp32 -> bf16 conversion of all tensors (grid-stride, 8 elems/thread/iter)
__global__ __launch_bounds__(256) void cvt6(
    const float* __restrict__ q, const float* __restrict__ k,
    const float* __restrict__ v, const float* __restrict__ wq,
    const float* __restrict__ wo, const float* __restrict__ wk,
    const float* __restrict__ wv,
    short* __restrict__ qo, short* __restrict__ ko, short* __restrict__ vo,
    short* __restrict__ wqo, short* __restrict__ woo, short* __restrict__ wko,
    short* __restrict__ wvo)
{
    const int NB = (MROWS * D_MODEL) / 8;
    const int NW = (D_MODEL * D_MODEL) / 8;
    const int NS = (DK * D_MODEL) / 8;
    const int total = 3 * NB + 2 * NW + 2 * NS;
    for (int g = blockIdx.x * 256 + threadIdx.x; g < total; g += gridDim.x * 256) {
        const float* s; short* d; int x = g;
        if (x < NB)            { s = q;  d = qo;  }
        else if ((x -= NB) < NB) { s = k;  d = ko;  }
        else if ((x -= NB) < NB) { s = v;  d = vo;  }
        else if ((x -= NB) < NW) { s = wq; d = wqo; }
        else if ((x -= NW) < NW) { s = wo; d = woo; }
        else if ((x -= NW) < NS) { s = wk; d = wko; }
        else                     { x -= NS; s = wv; d = wvo; }
        float4 a = ((const float4*)s)[x * 2];
        float4 b = ((const float4*)s)[x * 2 + 1];
        uint4 hv;
        hv.x = pkbf2(a.x, a.y); hv.y = pkbf2(a.z, a.w);
        hv.z = pkbf2(b.x, b.y); hv.w = pkbf2(b.z, b.w);
        ((uint4*)d)[x] = hv;
    }
}

// C[M,N] = (A[M,K] @ W[N,K]^T + bias[N]) * outmult, all-bf16 in, gload_lds staging.
// MODE 0: bf16 out. MODE 1: fp32 out. MODE 2: blockIdx.y selects K-proj/V-proj(T).
// V-proj (sel=1) stores key columns sigma-permuted within each 64-key group so
// the attention PV step can consume P directly from registers (see mqa_attn_lds).
template<int MODE, int BM, int BN>
__global__ __launch_bounds__(256) void gemm97(
    const short* __restrict__ A, const short* __restrict__ W,
    const float* __restrict__ bias, void* __restrict__ Cp,
    const short* __restrict__ A2, const short* __restrict__ W2,
    const float* __restrict__ bias2, void* __restrict__ Cp2,
    int M, int N, int K, float outmult)
{
    constexpr int MI = BM / 32;
    constexpr int NI = BN / 32;
    constexpr int ACH = BM / 32;
    constexpr int WCH = BN / 32;
    __shared__ short As[BM * 64];
    __shared__ short Ws[BN * 64];

    int sel = 0;
    if (MODE == 2) {
        sel = blockIdx.y;
        if (sel) { A = A2; W = W2; bias = bias2; Cp = Cp2; }
    }
    const int bm = blockIdx.x * BM;
    const int bn = (MODE == 2) ? 0 : blockIdx.y * BN;
    const int tid = threadIdx.x;
    const int l = tid & 63, w = tid >> 6;
    const int lr = l & 15, lg = l >> 4;
    const int wm = (w >> 1) * (BM / 2), wn = (w & 1) * (BN / 2);

    f32x4 acc[MI][NI];
    #pragma unroll
    for (int mi = 0; mi < MI; mi++)
        #pragma unroll
        for (int ni = 0; ni < NI; ni++)
            acc[mi][ni] = (f32x4){0.f, 0.f, 0.f, 0.f};

    const int srow = l >> 3;
    const int scol = (l & 7) * 8;

    for (int k0 = 0; k0 < K; k0 += 64) {
        __syncthreads();
        #pragma unroll
        for (int i = 0; i < ACH; i++) {
            int c = w * ACH + i;
            gload16(A + (size_t)(bm + 8 * c + srow) * K + k0 + scol, As + c * 512);
        }
        #pragma unroll
        for (int i = 0; i < WCH; i++) {
            int c = w * WCH + i;
            gload16(W + (size_t)(bn + 8 * c + srow) * K + k0 + scol, Ws + c * 512);
        }
        __syncthreads();
        #pragma unroll
        for (int ks = 0; ks < 2; ks++) {
            bf16x8 af[MI], bf[NI];
            #pragma unroll
            for (int mi = 0; mi < MI; mi++)
                af[mi] = *(const bf16x8*)&As[(wm + mi * 16 + lr) * 64 + ks * 32 + 8 * lg];
            #pragma unroll
            for (int ni = 0; ni < NI; ni++)
                bf[ni] = *(const bf16x8*)&Ws[(wn + ni * 16 + lr) * 64 + ks * 32 + 8 * lg];
            #pragma unroll
            for (int mi = 0; mi < MI; mi++)
                #pragma unroll
                for (int ni = 0; ni < NI; ni++)
                    acc[mi][ni] = __builtin_amdgcn_mfma_f32_16x16x32_bf16(
                        af[mi], bf[ni], acc[mi][ni], 0, 0, 0);
        }
    }

    #pragma unroll
    for (int ni = 0; ni < NI; ni++) {
        int col = bn + wn + ni * 16 + lr;
        float bv = bias[col];
        #pragma unroll
        for (int mi = 0; mi < MI; mi++) {
            #pragma unroll
            for (int r = 0; r < 4; r++) {
                int row = bm + wm + mi * 16 + lg * 4 + r;
                float val = (acc[mi][ni][r] + bv) * outmult;
                if (MODE == 0) {
                    ((short*)Cp)[(size_t)row * N + col] = f2bf(val);
                } else if (MODE == 1) {
                    ((float*)Cp)[(size_t)row * N + col] = val;
                } else {
                    if (sel == 0) {
                        ((short*)Cp)[(size_t)row * DK + col] = f2bf(val);
                    } else {
                        int bi = row >> 11, si = row & (SEQ - 1);
                        // sigma^-1 permute key index within its 64-key group:
                        // c = (s&32) | ((s>>3 &1)<<4) | ((s>>2 &1)<<3) | ((s>>4 &1)<<2) | (s&3)
                        int s6 = si & 63;
                        int sperm = (si & ~63) | (s6 & 32) |
                                    (((s6 >> 3) & 1) << 4) | (((s6 >> 2) & 1) << 3) |
                                    (((s6 >> 4) & 1) << 2) | (s6 & 3);
                        ((short*)Cp)[((size_t)bi * DK + col) * SEQ + sperm] = f2bf(val);
                    }
                }
            }
        }
    }
}

// Flash MQA attention: block-shared double-buffered K/V in LDS (32KB total).
// 4 waves x 16 q-rows = 64 q-rows/block; grid (SEQ/64, H, B) = 1024 blocks.
// Swapped operands: S^T = K.Q^T, O^T = V^T.P^T (per-lane softmax stats).
// P never touches LDS: V^T stored with sigma-permuted key columns
// (sigma(c): s5=c5,s4=c2,s3s2=c4c3,s1s0=c1c0) so each lane's own 16 scores
// ARE the PV B-fragment -> pf packed from registers, zero cross-lane ops.
// K tile [64 keys][64 dk], V^T tile [64 dk][64 keys], XOR-swizzled
// (byte ^= (row&7)<<4) via pre-swizzled GLOBAL source + linear gload_lds dest.
// qb PRE-SCALED by log2(e)/8 -> exp2-domain softmax; lazy cross-lane max.
__global__ __launch_bounds__(256, 4) void mqa_attn_lds(
    const short* __restrict__ qb, const short* __restrict__ kb,
    const short* __restrict__ vt, short* __restrict__ ob)
{
    __shared__ char KsB[2][64 * 128];
    __shared__ char VsB[2][64 * 128];
    const int h = blockIdx.y, b = blockIdx.z;
    const int tid = threadIdx.x;
    const int l = tid & 63, w = tid >> 6;
    const int lr = l & 15, lg = l >> 4;
    const int q0 = blockIdx.x * 64 + w * 16;

    // Q fragments (registers, whole kernel)
    bf16x8 qf[2];
    #pragma unroll
    for (int kk = 0; kk < 2; kk++)
        qf[kk] = *(const bf16x8*)(
            qb + (size_t)(b * SEQ + q0 + lr) * D_MODEL + h * DK + kk * 32 + 8 * lg);

    // staging source indices (per-lane, loop-invariant parts)
    int srow[2], scol[2];
    #pragma unroll
    for (int i = 0; i < 2; i++) {
        int s = i * 256 + w * 64 + l;
        srow[i] = s >> 3;
        int cb = (s & 7) * 16;
        scol[i] = (cb ^ ((srow[i] & 7) << 4)) >> 1;   // short offset within row
    }

    f32x4 o[4];
    #pragma unroll
    for (int dt = 0; dt < 4; dt++)
        o[dt] = (f32x4){0.f, 0.f, 0.f, 0.f};
    float m_i = -1e30f;   // row-uniform running max (log2 domain)
    float l_l = 0.f;      // PER-LANE partial sum; reduced in epilogue

    // prologue: stage tile 0 into buffer 0
    #pragma unroll
    for (int i = 0; i < 2; i++) {
        gload16(kb + (size_t)(b * SEQ + 0 + srow[i]) * DK + scol[i],
                KsB[0] + (i * 256 + w * 64) * 16);
        gload16(vt + (size_t)(b * DK + srow[i]) * SEQ + 0 + scol[i],
                VsB[0] + (i * 256 + w * 64) * 16);
    }

    for (int t = 0; t < SEQ / 64; t++) {
        const int cur = t & 1;
        const int kt = t * 64;
        __syncthreads();   // drains this thread's tile-t loads; all waves' data in LDS
        if (t + 1 < SEQ / 64) {
            const int ktn = kt + 64;
            #pragma unroll
            for (int i = 0; i < 2; i++) {
                gload16(kb + (size_t)(b * SEQ + ktn + srow[i]) * DK + scol[i],
                        KsB[cur ^ 1] + (i * 256 + w * 64) * 16);
                gload16(vt + (size_t)(b * DK + srow[i]) * SEQ + ktn + scol[i],
                        VsB[cur ^ 1] + (i * 256 + w * 64) * 16);
            }
        }
        const char* Kc = KsB[cur];
        const char* Vc = VsB[cur];

        // ---- S^T = K . Q^T ----  (16 q-rows x 64 keys per wave)
        f32x4 s[4];
        #pragma unroll
        for (int j = 0; j < 4; j++) s[j] = (f32x4){0.f, 0.f, 0.f, 0.f};
        #pragma unroll
        for (int kk = 0; kk < 2; kk++) {
            bf16x8 kf[4];
            #pragma unroll
            for (int j = 0; j < 4; j++) {
                int row = j * 16 + lr;
                kf[j] = *(const bf16x8*)(Kc + row * 128 + ((kk * 64 + 16 * lg) ^ ((row & 7) << 4)));
            }
            __builtin_amdgcn_s_setprio(1);
            #pragma unroll
            for (int j = 0; j < 4; j++)
                s[j] = __builtin_amdgcn_mfma_f32_16x16x32_bf16(
                    kf[j], qf[kk], s[j], 0, 0, 0);
            __builtin_amdgcn_s_setprio(0);
        }

        // ---- V fragments: issue early so ds latency hides under softmax ----
        bf16x8 vf[2][4];
        #pragma unroll
        for (int kk = 0; kk < 2; kk++)
            #pragma unroll
            for (int dt = 0; dt < 4; dt++) {
                int row = dt * 16 + lr;
                vf[kk][dt] = *(const bf16x8*)(Vc + row * 128 + ((kk * 64 + 16 * lg) ^ ((row & 7) << 4)));
            }

        // ---- per-lane online softmax (exp2 domain), lazy cross-lane max ----
        union { unsigned u[4]; bf16x8 v; } pku[2];
        {
            float mA = fmaxf(fmaxf(s[0][0], s[0][1]), s[0][2]);
            float mB = fmaxf(fmaxf(s[0][3], s[1][0]), s[1][1]);
            float mC = fmaxf(fmaxf(s[1][2], s[1][3]), s[2][0]);
            float mD = fmaxf(fmaxf(s[2][1], s[2][2]), s[2][3]);
            float mE = fmaxf(fmaxf(s[3][0], s[3][1]), s[3][2]);
            float mx = fmaxf(fmaxf(fmaxf(mA, mB), mC),
                             fmaxf(fmaxf(mD, mE), s[3][3]));

            if (__any(mx > m_i + 8.0f)) {   // wave-uniform, rare (first tile)
                float mxf = fmaxf(mx, __shfl_xor(mx, 16));
                mxf = fmaxf(mxf, __shfl_xor(mxf, 32));
                float mn = fmaxf(m_i, mxf);
                float corr = __builtin_amdgcn_exp2f(m_i - mn);
                m_i = mn;
                l_l *= corr;
                #pragma unroll
                for (int dt = 0; dt < 4; dt++)
                    o[dt] *= corr;
            }
            const float mnv = m_i;

            float p[4][4];
            float rs = 0.f;
            #pragma unroll
            for (int j = 0; j < 4; j++) {
                p[j][0] = __builtin_amdgcn_exp2f(s[j][0] - mnv);
                p[j][1] = __builtin_amdgcn_exp2f(s[j][1] - mnv);
                p[j][2] = __builtin_amdgcn_exp2f(s[j][2] - mnv);
                p[j][3] = __builtin_amdgcn_exp2f(s[j][3] - mnv);
                rs += (p[j][0] + p[j][1]) + (p[j][2] + p[j][3]);
            }
            l_l += rs;   // per-lane partial; no cross-lane reduce here

            // pack own 16 scores into the two PV B-fragments (sigma layout)
            pku[0].u[0] = pkbf2(p[0][0], p[0][1]);
            pku[0].u[1] = pkbf2(p[0][2], p[0][3]);
            pku[0].u[2] = pkbf2(p[1][0], p[1][1]);
            pku[0].u[3] = pkbf2(p[1][2], p[1][3]);
            pku[1].u[0] = pkbf2(p[2][0], p[2][1]);
            pku[1].u[1] = pkbf2(p[2][2], p[2][3]);
            pku[1].u[2] = pkbf2(p[3][0], p[3][1]);
            pku[1].u[3] = pkbf2(p[3][2], p[3][3]);
        }

        // ---- O^T += V^T . P^T  (P straight from registers) ----
        __builtin_amdgcn_s_setprio(1);
        #pragma unroll
        for (int kk = 0; kk < 2; kk++)
            #pragma unroll
            for (int dt = 0; dt < 4; dt++)
                o[dt] = __builtin_amdgcn_mfma_f32_16x16x32_bf16(
                    vf[kk][dt], pku[kk].v, o[dt], 0, 0, 0);
        __builtin_amdgcn_s_setprio(0);
    }

    // ---- epilogue: reduce per-lane l across the 4 lane-groups, normalize ----
    float lt = l_l;
    lt += __shfl_xor(lt, 16);
    lt += __shfl_xor(lt, 32);
    float inv = 1.0f / lt;
    size_t grow = (size_t)(b * SEQ + q0 + lr);
    #pragma unroll
    for (int dt = 0; dt < 4; dt++) {
        uint2 pk;
        pk.x = pkbf2(o[dt][0] * inv, o[dt][1] * inv);
        pk.y = pkbf2(o[dt][2] * inv, o[dt][3] * inv);
        *(uint2*)(ob + grow * D_MODEL + h * DK + dt * 16 + lg * 4) = pk;
    }
}

extern "C" void kernel_launch(void* const* d_in, const int* in_sizes, int n_in,
                              void* d_out, int out_size, void* d_ws, size_t ws_size,
                              hipStream_t stream) {
    const float* Q   = (const float*)d_in[0];
    const float* K   = (const float*)d_in[1];
    const float* V   = (const float*)d_in[2];
    const float* W_Q = (const float*)d_in[3];
    const float* b_Q = (const float*)d_in[4];
    const float* W_K = (const float*)d_in[5];
    const float* b_K = (const float*)d_in[6];
    const float* W_V = (const float*)d_in[7];
    const float* b_V = (const float*)d_in[8];
    const float* W_O = (const float*)d_in[9];
    const float* b_O = (const float*)d_in[10];
    float* out = (float*)d_out;

    short* Qb  = (short*)d_ws;
    short* Kb  = Qb  + (size_t)MROWS * D_MODEL;
    short* Vb  = Kb  + (size_t)MROWS * D_MODEL;
    short* WQb = Vb  + (size_t)MROWS * D_MODEL;
    short* WKb = WQb + (size_t)D_MODEL * D_MODEL;
    short* WVb = WKb + (size_t)DK * D_MODEL;
    short* WOb = WVb + (size_t)DK * D_MODEL;
    short* qb  = WOb + (size_t)D_MODEL * D_MODEL;
    short* kb  = qb  + (size_t)MROWS * D_MODEL;
    short* vt  = kb  + (size_t)MROWS * DK;
    short* aws = vt  + (size_t)MROWS * DK;

    cvt6<<<2048, 256, 0, stream>>>(Q, K, V, W_Q, W_O, W_K, W_V,
                                   Qb, Kb, Vb, WQb, WOb, WKb, WVb);

    // Q projection, pre-scaled by log2(e)/sqrt(dk) (exp2-domain softmax)
    gemm97<0, 64, 128><<<dim3(MROWS / 64, D_MODEL / 128), 256, 0, stream>>>(
        Qb, WQb, b_Q, qb, nullptr, nullptr, nullptr, nullptr,
        MROWS, D_MODEL, D_MODEL, QSCALE);
    // K + V projections fused by blockIdx.y (V stored sigma-permuted)
    gemm97<2, 64, 64><<<dim3(MROWS / 64, 2), 256, 0, stream>>>(
        Kb, WKb, b_K, kb, Vb, WVb, b_V, vt, MROWS, DK, D_MODEL, 1.0f);
    // attention: 64 q-rows/block, 1024 blocks, 4 blocks/CU (32KB LDS)
    mqa_attn_lds<<<dim3(SEQ / 64, NUM_HEADS, BATCH), 256, 0, stream>>>(
        qb, kb, vt, aws);
    // output projection (fp32 out)
    gemm97<1, 64, 128><<<dim3(MROWS / 64, D_MODEL / 128), 256, 0, stream>>>(
        aws, WOb, b_O, out, nullptr, nullptr, nullptr, nullptr,
        MROWS, D_MODEL, D_MODEL, 1.0f);
}